// Round 11
// baseline (76.372 us; speedup 1.0000x reference)
//
#include <hip/hip_runtime.h>

#define NC 1024
#define DY 16
#define NG 65536

#define SZ_YTB (32 * 64 * 8)   // h16 per m: [ks][lane][jj]  B-frag order (64 KB/m)

typedef float v4f __attribute__((ext_vector_type(4)));
typedef _Float16 h8 __attribute__((ext_vector_type(8)));

// ---- K1: tiny YTB builder (16 blocks). One (ks,lane) cell per thread. ----
__global__ __launch_bounds__(256) void setconv_ytb(
    const float* __restrict__ yc, _Float16* __restrict__ YTB, int m)
{
    const int t = blockIdx.x * 256 + threadIdx.x;
    if (t >= m * 2048) return;
    const int mm   = t >> 11;
    const int cell = t & 2047;
    const int lane = cell & 63;
    const int ks   = cell >> 6;
    const int ch   = lane & 15;
    const int k0   = ks * 32 + ((lane >> 4) << 3);
    h8 o;
#pragma unroll
    for (int jj = 0; jj < 8; ++jj)
        o[jj] = (_Float16)yc[(((size_t)(mm * NC + k0 + jj)) << 4) + ch];
    *(h8*)&YTB[(size_t)t * 8] = o;
}

// ---- K2: block = 16 i x 16 j (one jt), 4 waves (wave w -> i-rows w*4..w*4+3).
// All K-loop operands LDS-resident (wyA A-frag 32 KB + wx16 plain 32 KB = 64 KB
// -> 2 blocks/CU, 512 blocks = one residency round) except yt: a 64 KB global
// stream identical for every block (L1-broadcast). Prologue: 32K exps/block
// (~0.4 us), off the K-loop. Density channel via ones-B MFMA. ----
__global__ __launch_bounds__(256, 2) void setconv_main(
    const float* __restrict__ xc,   // [m, NC, 2]
    const float* __restrict__ lsp,  // [2]
    const _Float16* __restrict__ YTB,
    float* __restrict__ out_grid,   // [m, 256, 256, 2]
    float* __restrict__ out_z)      // [m, 256, 256, 17]
{
    __shared__ __align__(16) _Float16 wyA[2048 * 8];   // 32 KB [ks][lane][jj]
    __shared__ __align__(16) _Float16 wx16[16][NC];    // 32 KB

    const int mi   = blockIdx.y;
    const int bx   = blockIdx.x;     // 0..255
    const int ig   = bx >> 4;        // 0..15
    const int jg   = bx & 15;        // 0..15
    const int tid  = threadIdx.x;
    const int wave = tid >> 6;
    const int lane = tid & 63;
    const int q    = lane >> 4;
    const int r    = lane & 15;
    const int i0   = ig * 16;
    const int j0   = jg * 16;

    const float l0 = 1e-5f + __logf(1.0f + __expf(lsp[0]));
    const float l1 = 1e-5f + __logf(1.0f + __expf(lsp[1]));
    const float R  = 0.84932184f;    // sqrt(log2(e)/2)
    const float s0 = R / l0, s1 = R / l1;

    // out_grid: one point per thread (i = i0+tid>>4, j = j0+tid&15)
    {
        const int i = i0 + (tid >> 4), j = j0 + (tid & 15);
        const float gx = 1.0f + (float)(i - 128) * 0.015625f;
        const float gy = 1.0f + (float)(j - 128) * 0.015625f;
        ((float2*)out_grid)[(size_t)mi * NG + i * 256 + j] = make_float2(gx, gy);
    }

    // ---- prologue: wyA (A-frag order, this block's jt) ----
#pragma unroll
    for (int c = 0; c < 8; ++c) {
        const int cell = tid + 256 * c;        // 0..2047 = ks*64+lane
        const int ks = cell >> 6, ln = cell & 63;
        const int rr = ln & 15, qq = ln >> 4;
        const int k0 = ks * 32 + qq * 8;
        const float gy = (1.0f + (float)(j0 + rr - 128) * 0.015625f) * s1;
        h8 o;
#pragma unroll
        for (int jj = 0; jj < 8; ++jj) {
            const float u = gy - xc[(((size_t)mi * NC + k0 + jj) << 1) + 1] * s1;
            o[jj] = (_Float16)__builtin_amdgcn_exp2f(-u * u);
        }
        *(h8*)&wyA[(size_t)cell * 8] = o;
    }
    // ---- prologue: wx16 (plain [i][k]) ----
#pragma unroll
    for (int c = 0; c < 8; ++c) {
        const int idx = tid + 256 * c;         // 0..2047
        const int il = idx >> 7, k0 = (idx & 127) << 3;
        const float gx = (1.0f + (float)(i0 + il - 128) * 0.015625f) * s0;
        h8 o;
#pragma unroll
        for (int jj = 0; jj < 8; ++jj) {
            const float u = gx - xc[((size_t)mi * NC + k0 + jj) << 1] * s0;
            o[jj] = (_Float16)__builtin_amdgcn_exp2f(-u * u);
        }
        *(h8*)&wx16[0][idx * 8] = o;
    }
    __syncthreads();

    const _Float16* ytp = YTB + ((size_t)mi * 2048 + lane) * 8;

    h8 ones;
#pragma unroll
    for (int e = 0; e < 8; ++e) ones[e] = (_Float16)1.0f;

    v4f accD[4], accS[4];
#pragma unroll
    for (int ii = 0; ii < 4; ++ii) {
        accD[ii] = (v4f){0.f, 0.f, 0.f, 0.f};
        accS[ii] = (v4f){0.f, 0.f, 0.f, 0.f};
    }

#pragma unroll 4
    for (int ks = 0; ks < 32; ++ks) {
        const h8 yt = *(const h8*)(ytp + (size_t)ks * 512);             // global, L1-hot
        const h8 wy = *(const h8*)&wyA[((size_t)ks * 64 + lane) * 8];   // ds_read_b128
#pragma unroll
        for (int ii = 0; ii < 4; ++ii) {
            const h8 wx = *(const h8*)&wx16[wave * 4 + ii][ks * 32 + q * 8];  // quad-uniform
            const h8 a  = wy * wx;                                            // 4x v_pk_mul_f16
            accD[ii] = __builtin_amdgcn_mfma_f32_16x16x32_f16(a, yt,   accD[ii], 0, 0, 0);
            accS[ii] = __builtin_amdgcn_mfma_f32_16x16x32_f16(a, ones, accS[ii], 0, 0, 0);
        }
    }

    // C/D: col(lane&15)=channel, row(q*4+reg)=j within jt (validated r3-r10)
#pragma unroll
    for (int ii = 0; ii < 4; ++ii) {
        const int i = i0 + wave * 4 + ii;
        float* __restrict__ oz = out_z + ((size_t)mi * NG + (size_t)i * 256 + j0) * 17;
#pragma unroll
        for (int reg = 0; reg < 4; ++reg) {
            const int row = q * 4 + reg;
            oz[(size_t)row * 17 + r] = accD[ii][reg];
            if (r == 0) oz[(size_t)row * 17 + 16] = accS[ii][reg];
        }
    }
}

extern "C" void kernel_launch(void* const* d_in, const int* in_sizes, int n_in,
                              void* d_out, int out_size, void* d_ws, size_t ws_size,
                              hipStream_t stream) {
    const float* xc  = (const float*)d_in[0];   // [m, 1024, 2]
    const float* yc  = (const float*)d_in[1];   // [m, 1024, 16]
    // d_in[2] = xt — unused by the reference output
    const float* lsp = (const float*)d_in[3];   // [2]

    int m = in_sizes[0] / (NC * 2);             // = 2

    float* out_grid = (float*)d_out;
    float* out_z    = (float*)d_out + (size_t)m * NG * 2;

    _Float16* YTB = (_Float16*)d_ws;            // m * 16384 h16 = 64 KB/m

    hipLaunchKernelGGL(setconv_ytb, dim3((m * 2048 + 255) / 256), dim3(256),
                       0, stream, yc, YTB, m);

    hipLaunchKernelGGL(setconv_main, dim3(256, m), dim3(256), 0, stream,
                       xc, lsp, YTB, out_grid, out_z);
}

// Round 12
// 73.356 us; speedup vs baseline: 1.0411x; 1.0411x over previous
//
#include <hip/hip_runtime.h>

#define NC 1024
#define DY 16
#define NG 65536

#define SZ_WYA (16 * 32 * 64 * 8)  // h16 per m: [jt][ks][lane][jj] A-frag order
#define SZ_YTB (32 * 64 * 8)       // h16 per m: [ks][lane][jj]     B-frag order

typedef float v4f __attribute__((ext_vector_type(4)));
typedef _Float16 h8 __attribute__((ext_vector_type(8)));

// ---- K1: table builder (272 blocks). 8 exps + one 16B store per thread. ----
__global__ __launch_bounds__(256) void setconv_tables(
    const float* __restrict__ xc, const float* __restrict__ yc,
    const float* __restrict__ lsp,
    _Float16* __restrict__ WYA, _Float16* __restrict__ YTB, int m)
{
    const int t  = blockIdx.x * 256 + threadIdx.x;
    const int T1 = m * (SZ_WYA / 8);
    const int T2 = T1 + m * (SZ_YTB / 8);
    if (t >= T2) return;

    if (t < T1) {
        const float l1 = 1e-5f + __logf(1.0f + __expf(lsp[1]));
        const float s1 = 0.84932184f / l1;          // sqrt(log2e/2)/l
        const int mm   = t >> 15;
        const int rem  = t & 32767;
        const int jt   = rem >> 11;
        const int ks   = (rem >> 6) & 31;
        const int lane = rem & 63;
        const int j    = jt * 16 + (lane & 15);
        const int k0   = ks * 32 + ((lane >> 4) << 3);
        const float g  = (1.0f + (float)(j - 128) * 0.015625f) * s1;
        h8 o;
#pragma unroll
        for (int jj = 0; jj < 8; ++jj) {
            const float u = g - xc[(((size_t)(mm * NC + k0 + jj)) << 1) + 1] * s1;
            o[jj] = (_Float16)__builtin_amdgcn_exp2f(-u * u);
        }
        *(h8*)&WYA[(size_t)t * 8] = o;
    } else {
        const int tt   = t - T1;
        const int mm   = tt >> 11;
        const int rem  = tt & 2047;
        const int ks   = rem >> 6;
        const int lane = rem & 63;
        const int ch   = lane & 15;
        const int k0   = ks * 32 + ((lane >> 4) << 3);
        h8 o;
#pragma unroll
        for (int jj = 0; jj < 8; ++jj)
            o[jj] = (_Float16)yc[(((size_t)(mm * NC + k0 + jj)) << 4) + ch];
        *(h8*)&YTB[(size_t)tt * 8] = o;
    }
}

// ---- K2: occupancy experiment. 128-thr blocks (2 waves), block = 2 i x 32 j,
// grid = 2048 = 8 blocks/CU x 256 CU. LDS 12 KB: ytb K-tiled in 8 KB slabs
// (4 slabs, single-buffered) + wx2 4 KB. K-loop identical to R9 (best). ----
__global__ __launch_bounds__(128, 8) void setconv_main(
    const float* __restrict__ xc,   // [m, NC, 2]
    const float* __restrict__ lsp,  // [2]
    const _Float16* __restrict__ WYA,
    const _Float16* __restrict__ YTB,
    float* __restrict__ out_grid,   // [m, 256, 256, 2]
    float* __restrict__ out_z)      // [m, 256, 256, 17]
{
    __shared__ __align__(16) _Float16 ytb[8 * 64 * 8];   // 8 KB slab (256 k)
    __shared__ __align__(16) _Float16 wx2[2][NC];        // 4 KB

    const int mi   = blockIdx.y;
    const int bx   = blockIdx.x;     // 0..1023
    const int ig   = bx >> 3;        // 0..127 -> i0 = 2*ig
    const int jg   = bx & 7;         // 0..7   -> j0 = 32*jg
    const int tid  = threadIdx.x;    // 0..127
    const int wave = tid >> 6;       // 0..1
    const int lane = tid & 63;
    const int q    = lane >> 4;
    const int r    = lane & 15;
    const int jt   = jg * 2 + wave;  // 0..15
    const int i0   = ig * 2;

    const float l0 = 1e-5f + __logf(1.0f + __expf(lsp[0]));
    const float s0 = 0.84932184f / l0;

    // out_grid: this block's 2x32 tile (threads 0..63)
    if (tid < 64) {
        const int i = i0 + (tid >> 5), j = jg * 32 + (tid & 31);
        const float gx = 1.0f + (float)(i - 128) * 0.015625f;
        const float gy = 1.0f + (float)(j - 128) * 0.015625f;
        ((float2*)out_grid)[(size_t)mi * NG + i * 256 + j] = make_float2(gx, gy);
    }

    // prologue: wx rows (2048 exps over 128 threads)
#pragma unroll
    for (int t = 0; t < 16; ++t) {
        const int idx = tid + 128 * t;
        const int row = idx >> 10, k = idx & 1023;
        const float gi = (1.0f + (float)(i0 + row - 128) * 0.015625f) * s0;
        const float u  = gi - xc[((size_t)mi * NC + k) << 1] * s0;
        wx2[row][k] = (_Float16)__builtin_amdgcn_exp2f(-u * u);
    }

    const _Float16* wyp = WYA + (((size_t)mi * 16 + jt) * 32 * 64 + lane) * 8;

    h8 ones;
#pragma unroll
    for (int e = 0; e < 8; ++e) ones[e] = (_Float16)1.0f;

    v4f accD0 = {0.f,0.f,0.f,0.f}, accS0 = {0.f,0.f,0.f,0.f};
    v4f accD1 = {0.f,0.f,0.f,0.f}, accS1 = {0.f,0.f,0.f,0.f};

    for (int slab = 0; slab < 4; ++slab) {
        // stage 8 KB ytb slab (linear float4: 512 / 128 thr = 4 each)
        {
            const float4* src =
                (const float4*)(YTB + (size_t)mi * SZ_YTB + (size_t)slab * 4096);
            float4* dst = (float4*)ytb;
#pragma unroll
            for (int tt = 0; tt < 4; ++tt) dst[tid + 128 * tt] = src[tid + 128 * tt];
        }
        __syncthreads();

#pragma unroll
        for (int kk = 0; kk < 8; ++kk) {
            const int ks = slab * 8 + kk;
            const h8 wy  = *(const h8*)(wyp + (size_t)ks * 512);            // global dwordx4
            const h8 yt  = *(const h8*)&ytb[((size_t)kk * 64 + lane) * 8];  // ds_read_b128
            const h8 wxa = *(const h8*)&wx2[0][ks * 32 + q * 8];            // quad-broadcast
            const h8 wxb = *(const h8*)&wx2[1][ks * 32 + q * 8];
            const h8 a0 = wy * wxa;   // 4x v_pk_mul_f16
            const h8 a1 = wy * wxb;
            accD0 = __builtin_amdgcn_mfma_f32_16x16x32_f16(a0, yt,   accD0, 0, 0, 0);
            accS0 = __builtin_amdgcn_mfma_f32_16x16x32_f16(a0, ones, accS0, 0, 0, 0);
            accD1 = __builtin_amdgcn_mfma_f32_16x16x32_f16(a1, yt,   accD1, 0, 0, 0);
            accS1 = __builtin_amdgcn_mfma_f32_16x16x32_f16(a1, ones, accS1, 0, 0, 0);
        }
        __syncthreads();
    }

    // C/D: col(lane&15)=channel, row(q*4+reg)=j within jt (validated r3-r11)
    float* __restrict__ oz0 =
        out_z + ((size_t)mi * NG + (size_t)i0 * 256 + jt * 16) * 17;
    float* __restrict__ oz1 = oz0 + 256 * 17;
#pragma unroll
    for (int reg = 0; reg < 4; ++reg) {
        const int row = q * 4 + reg;
        oz0[(size_t)row * 17 + r] = accD0[reg];
        oz1[(size_t)row * 17 + r] = accD1[reg];
        if (r == 0) {
            oz0[(size_t)row * 17 + 16] = accS0[reg];
            oz1[(size_t)row * 17 + 16] = accS1[reg];
        }
    }
}

extern "C" void kernel_launch(void* const* d_in, const int* in_sizes, int n_in,
                              void* d_out, int out_size, void* d_ws, size_t ws_size,
                              hipStream_t stream) {
    const float* xc  = (const float*)d_in[0];   // [m, 1024, 2]
    const float* yc  = (const float*)d_in[1];   // [m, 1024, 16]
    // d_in[2] = xt — unused by the reference output
    const float* lsp = (const float*)d_in[3];   // [2]

    int m = in_sizes[0] / (NC * 2);             // = 2

    float* out_grid = (float*)d_out;
    float* out_z    = (float*)d_out + (size_t)m * NG * 2;

    _Float16* WYA = (_Float16*)d_ws;
    _Float16* YTB = WYA + (size_t)m * SZ_WYA;

    const int total1 = m * (SZ_WYA / 8 + SZ_YTB / 8);
    hipLaunchKernelGGL(setconv_tables, dim3((total1 + 255) / 256), dim3(256),
                       0, stream, xc, yc, lsp, WYA, YTB, m);

    hipLaunchKernelGGL(setconv_main, dim3(1024, m), dim3(128), 0, stream,
                       xc, lsp, WYA, YTB, out_grid, out_z);
}